// Round 9
// baseline (153.205 us; speedup 1.0000x reference)
//
#include <hip/hip_runtime.h>

#define NJ 22
#define TILE 128          // poses per block
#define PW 121            // LDS words per pose: 120 data (joints 2..21) + 1 pad; ODD => conflict-free b32 reads

__device__ __forceinline__ void rot6d_to_mat(float a1x, float a1y, float a1z,
                                             float a2x, float a2y, float a2z,
                                             float* R) {
    float n1 = sqrtf(a1x * a1x + a1y * a1y + a1z * a1z);
    float inv1 = 1.0f / fmaxf(n1, 1e-12f);
    float b1x = a1x * inv1, b1y = a1y * inv1, b1z = a1z * inv1;
    float d = b1x * a2x + b1y * a2y + b1z * a2z;
    float b2x = a2x - b1x * d, b2y = a2y - b1y * d, b2z = a2z - b1z * d;
    float n2 = sqrtf(b2x * b2x + b2y * b2y + b2z * b2z);
    float inv2 = 1.0f / fmaxf(n2, 1e-12f);
    b2x *= inv2; b2y *= inv2; b2z *= inv2;
    float b3x = b1y * b2z - b1z * b2y;
    float b3y = b1z * b2x - b1x * b2z;
    float b3z = b1x * b2y - b1y * b2x;
    R[0] = b1x; R[1] = b2x; R[2] = b3x;
    R[3] = b1y; R[4] = b2y; R[5] = b3y;
    R[6] = b1z; R[7] = b2z; R[8] = b3z;
}

__device__ __forceinline__ void matmul3(const float* __restrict__ A,
                                        const float* __restrict__ B,
                                        float* __restrict__ C) {
#pragma unroll
    for (int r = 0; r < 3; ++r) {
#pragma unroll
        for (int c = 0; c < 3; ++c) {
            C[r * 3 + c] = A[r * 3 + 0] * B[0 * 3 + c]
                         + A[r * 3 + 1] * B[1 * 3 + c]
                         + A[r * 3 + 2] * B[2 * 3 + c];
        }
    }
}

// Block = 128 threads (2 waves) stages a 128-pose tile of gt_rot (joints 2..21)
// into LDS with fully-coalesced float4 loads (30 independent per thread —
// the memcpy pattern that reaches ~6.3 TB/s), then each thread runs the FK
// chain for its own pose out of LDS (odd 121-word stride -> conflict-free
// ds_read_b32, ~120cy latency instead of ~600cy HBM per dependent step).
// pred is prefetched per-thread (15 independent float4) before staging.
// LDS 62KB -> 2 blocks/CU: block B's staging overlaps block A's compute.
__global__ __launch_bounds__(128) void mpjpe_fk_kernel(
    const float4* __restrict__ pred4,     // [NP*15]  (=[NP,20,3] floats, 240B/pose)
    const float4* __restrict__ rot4,      // [NP*33]  (=[NP,22,6] floats, 528B/pose)
    const float* __restrict__ offsets,    // [22,3]
    float* __restrict__ out,              // [1]
    int nposes, float scale)              // scale = 1000 / (NP*20)
{
    constexpr int PAR[NJ] = {-1, 0, 0, 0, 1, 2, 3, 4, 5, 6, 7, 8, 9, 9, 9, 12, 13, 14, 16, 17, 18, 19};

    __shared__ float lds[TILE * PW];      // 61,952 B
    __shared__ float ws[2];

    const int tid  = threadIdx.x;
    const int base = blockIdx.x * TILE;
    const int pose = base + tid;

    // ---- per-thread pred prefetch (independent of staging) ----
    float pf[60];                          // pf[3*(j-2)] = pred x of joint j
    if (pose < nposes) {
        const float4* pp = pred4 + (size_t)pose * 15;
#pragma unroll
        for (int k = 0; k < 15; ++k) {
            float4 v = pp[k];
            pf[4*k+0] = v.x; pf[4*k+1] = v.y; pf[4*k+2] = v.z; pf[4*k+3] = v.w;
        }
    }

    // ---- cooperative coalesced stage: 128 poses x 30 f4 (joints 2..21) ----
    // iteration j: threads load consecutive f4 indices -> coalesced.
#pragma unroll
    for (int j = 0; j < 30; ++j) {
        int n = j * TILE + tid;            // 0..3839 tile-local f4 index
        int p = n / 30;                    // pose within tile (magic-mul)
        int q = n - p * 30;                // f4 within pose record (0..29)
        if (base + p < nposes) {
            float4 v = rot4[(size_t)(base + p) * 33 + 3 + q];   // skip joints 0,1 (3 f4)
            float* dst = &lds[p * PW + q * 4];
            dst[0] = v.x; dst[1] = v.y; dst[2] = v.z; dst[3] = v.w;
        }
    }
    __syncthreads();

    // ---- FK from LDS ----
    float sum = 0.0f;
    if (pose < nposes) {
        const float* rec = &lds[tid * PW]; // rec[6*(j-2)+c] = gt_rot float c of joint j

        float R[NJ][9];
        float P[NJ][3];

        R[0][0] = 1.f; R[0][1] = 0.f; R[0][2] = 0.f;
        R[0][3] = 0.f; R[0][4] = 1.f; R[0][5] = 0.f;
        R[0][6] = 0.f; R[0][7] = 0.f; R[0][8] = 1.f;
        P[0][0] = 0.f; P[0][1] = 0.f; P[0][2] = 0.f;

#pragma unroll
        for (int i = 1; i < NJ; ++i) {
            const int p = PAR[i];
            float ox = offsets[i * 3 + 0];
            float oy = offsets[i * 3 + 1];
            float oz = offsets[i * 3 + 2];
#pragma unroll
            for (int r = 0; r < 3; ++r) {
                P[i][r] = P[p][r] + R[p][r * 3 + 0] * ox
                                  + R[p][r * 3 + 1] * oy
                                  + R[p][r * 3 + 2] * oz;
            }
            if (i == 1) {
#pragma unroll
                for (int k = 0; k < 9; ++k) R[i][k] = R[p][k];
            } else {
                const int r0 = 6 * (i - 2);    // compile-time after unroll
                float M[9];
                rot6d_to_mat(rec[r0+0], rec[r0+1], rec[r0+2],
                             rec[r0+3], rec[r0+4], rec[r0+5], M);
                matmul3(R[p], M, R[i]);
            }
            if (i >= 2) {
                const int q0 = 3 * (i - 2);    // compile-time after unroll
                float dx = pf[q0+0] - P[i][0];
                float dy = pf[q0+1] - P[i][1];
                float dz = pf[q0+2] - P[i][2];
                sum += sqrtf(dx * dx + dy * dy + dz * dz);
            }
        }
    }

    // ---- reduction: 2 waves -> ws[2] -> one atomic ----
#pragma unroll
    for (int o = 32; o > 0; o >>= 1) sum += __shfl_down(sum, o, 64);

    const int lane = tid & 63;
    const int wid  = tid >> 6;
    if (lane == 0) ws[wid] = sum;
    __syncthreads();
    if (tid == 0) {
        atomicAdd(out, (ws[0] + ws[1]) * scale);
    }
}

extern "C" void kernel_launch(void* const* d_in, const int* in_sizes, int n_in,
                              void* d_out, int out_size, void* d_ws, size_t ws_size,
                              hipStream_t stream) {
    const float4* pred4 = (const float4*)d_in[0];
    const float4* rot4  = (const float4*)d_in[1];
    const float* offsets = (const float*)d_in[2];
    float* out = (float*)d_out;

    int nposes = in_sizes[1] / (NJ * 6);   // B*S = 131072
    float scale = 1000.0f / ((float)nposes * 20.0f);

    hipMemsetAsync(out, 0, sizeof(float), stream);

    int grid = (nposes + TILE - 1) / TILE; // 1024 blocks
    mpjpe_fk_kernel<<<grid, 128, 0, stream>>>(pred4, rot4, offsets, out, nposes, scale);
}

// Round 10
// 139.071 us; speedup vs baseline: 1.1016x; 1.1016x over previous
//
#include <hip/hip_runtime.h>

#define NJ 22
#define TILE 256
#define PW 62    // LDS words per pose slot: 60 data + 2 pad (even -> 8B-aligned float2 ops)

__device__ __forceinline__ void rot6d_to_mat(float a1x, float a1y, float a1z,
                                             float a2x, float a2y, float a2z,
                                             float* R) {
    float n1 = sqrtf(a1x * a1x + a1y * a1y + a1z * a1z);
    float inv1 = 1.0f / fmaxf(n1, 1e-12f);
    float b1x = a1x * inv1, b1y = a1y * inv1, b1z = a1z * inv1;
    float d = b1x * a2x + b1y * a2y + b1z * a2z;
    float b2x = a2x - b1x * d, b2y = a2y - b1y * d, b2z = a2z - b1z * d;
    float n2 = sqrtf(b2x * b2x + b2y * b2y + b2z * b2z);
    float inv2 = 1.0f / fmaxf(n2, 1e-12f);
    b2x *= inv2; b2y *= inv2; b2z *= inv2;
    float b3x = b1y * b2z - b1z * b2y;
    float b3y = b1z * b2x - b1x * b2z;
    float b3z = b1x * b2y - b1y * b2x;
    R[0] = b1x; R[1] = b2x; R[2] = b3x;
    R[3] = b1y; R[4] = b2y; R[5] = b3y;
    R[6] = b1z; R[7] = b2z; R[8] = b3z;
}

__device__ __forceinline__ void matmul3(const float* __restrict__ A,
                                        const float* __restrict__ B,
                                        float* __restrict__ C) {
#pragma unroll
    for (int r = 0; r < 3; ++r) {
#pragma unroll
        for (int c = 0; c < 3; ++c) {
            C[r * 3 + c] = A[r * 3 + 0] * B[0 * 3 + c]
                         + A[r * 3 + 1] * B[1 * 3 + c]
                         + A[r * 3 + 2] * B[2 * 3 + c];
        }
    }
}

// Coalesced stage of 15 float4s/pose (one 240B half-record or the pred record)
// into the shared tile buffer. n runs thread-linear over the tile -> global
// reads are the memcpy pattern (~93% contiguous); LDS writes are stride-1.
__device__ __forceinline__ void stage15(const float4* __restrict__ src,
                                        int src_stride_f4, int src_ofs_f4,
                                        int base, int nposes, int tid,
                                        float2* __restrict__ lds2, bool full) {
#pragma unroll
    for (int k = 0; k < 15; ++k) {
        int n = k * TILE + tid;
        int p = n / 15;                 // magic-mul
        int q = n - p * 15;
        if (full || base + p < nposes) {
            float4 v = src[(size_t)(base + p) * src_stride_f4 + src_ofs_f4 + q];
            int d = p * 31 + 2 * q;     // = (p*PW + 4q)/2
            lds2[d]     = make_float2(v.x, v.y);
            lds2[d + 1] = make_float2(v.z, v.w);
        }
    }
}

// Block = 256 threads / 256 poses. Three coalesced stage passes through ONE
// 61KB buffer: gt[2..11] -> FK(1..11) -> gt[12..21] -> FK(12..21, dists
// deferred, P[] held in regs) -> pred -> dists. 63.5KB LDS -> 2 blocks/CU
// (8 waves/CU); the two resident blocks run out of phase, overlapping one
// block's coalesced staging with the other's FK compute. Rationale: rounds
// 4-8 showed per-lane scattered reads cap at ~2.2 TB/s regardless of width/
// occupancy/fencing, while coalesced streams hit 6.5 TB/s on this chip.
__global__ __launch_bounds__(256, 2) void mpjpe_fk_kernel(
    const float4* __restrict__ pred4,     // [NP*15] (=[NP,20,3] floats)
    const float4* __restrict__ rot4,      // [NP*33] (=[NP,22,6] floats)
    const float* __restrict__ offsets,    // [22,3]
    float* __restrict__ out,              // [1]
    int nposes, float scale)              // scale = 1000 / (NP*20)
{
    constexpr int PAR[NJ] = {-1, 0, 0, 0, 1, 2, 3, 4, 5, 6, 7, 8, 9, 9, 9, 12, 13, 14, 16, 17, 18, 19};

    __shared__ float lds[TILE * PW];      // 63,488 B
    __shared__ float wsum[4];

    const int tid  = threadIdx.x;
    const int base = blockIdx.x * TILE;
    const int pose = base + tid;
    const bool full   = (base + TILE) <= nposes;
    const bool active = pose < nposes;
    float2* lds2 = (float2*)lds;
    const float2* myrec = (const float2*)&lds[tid * PW];   // 31*tid in f2 units

    float R[NJ][9];
    float P[NJ][3];

    // ---- stage A: gt_rot floats 12..71 (joints 2..11) = f4 3..17 ----
    stage15(rot4, 33, 3, base, nposes, tid, lds2, full);
    __syncthreads();

    // ---- FK joints 1..11 (joint j's 6 floats at slot float (j-2)*6) ----
    if (active) {
        R[0][0] = 1.f; R[0][1] = 0.f; R[0][2] = 0.f;
        R[0][3] = 0.f; R[0][4] = 1.f; R[0][5] = 0.f;
        R[0][6] = 0.f; R[0][7] = 0.f; R[0][8] = 1.f;
        P[0][0] = 0.f; P[0][1] = 0.f; P[0][2] = 0.f;
#pragma unroll
        for (int i = 1; i <= 11; ++i) {
            const int p = PAR[i];
            float ox = offsets[i * 3 + 0];
            float oy = offsets[i * 3 + 1];
            float oz = offsets[i * 3 + 2];
#pragma unroll
            for (int r = 0; r < 3; ++r) {
                P[i][r] = P[p][r] + R[p][r * 3 + 0] * ox
                                  + R[p][r * 3 + 1] * oy
                                  + R[p][r * 3 + 2] * oz;
            }
            if (i == 1) {
#pragma unroll
                for (int k = 0; k < 9; ++k) R[i][k] = R[p][k];
            } else {
                const int s = 3 * (i - 2);          // f2 index within slot
                float2 v0 = myrec[s + 0];
                float2 v1 = myrec[s + 1];
                float2 v2 = myrec[s + 2];
                float M[9];
                rot6d_to_mat(v0.x, v0.y, v1.x, v1.y, v2.x, v2.y, M);
                matmul3(R[p], M, R[i]);
            }
        }
    }
    __syncthreads();

    // ---- stage B: gt_rot floats 72..131 (joints 12..21) = f4 18..32 ----
    stage15(rot4, 33, 18, base, nposes, tid, lds2, full);
    __syncthreads();

    // ---- FK joints 12..21 (joint j at slot float (j-12)*6) ----
    if (active) {
#pragma unroll
        for (int i = 12; i < NJ; ++i) {
            const int p = PAR[i];
            float ox = offsets[i * 3 + 0];
            float oy = offsets[i * 3 + 1];
            float oz = offsets[i * 3 + 2];
#pragma unroll
            for (int r = 0; r < 3; ++r) {
                P[i][r] = P[p][r] + R[p][r * 3 + 0] * ox
                                  + R[p][r * 3 + 1] * oy
                                  + R[p][r * 3 + 2] * oz;
            }
            if (i < NJ - 1) {                       // R[21] never used
                const int s = 3 * (i - 12);
                float2 v0 = myrec[s + 0];
                float2 v1 = myrec[s + 1];
                float2 v2 = myrec[s + 2];
                float M[9];
                rot6d_to_mat(v0.x, v0.y, v1.x, v1.y, v2.x, v2.y, M);
                matmul3(R[p], M, R[i]);
            }
        }
    }
    __syncthreads();

    // ---- stage C: pred (15 f4/pose, linear stride 15) ----
    stage15(pred4, 15, 0, base, nposes, tid, lds2, full);
    __syncthreads();

    // ---- deferred distances: pred comp (j,r) at slot float (j-2)*3+r ----
    float sum = 0.0f;
    if (active) {
        float pf[60];
#pragma unroll
        for (int k = 0; k < 30; ++k) {
            float2 v = myrec[k];
            pf[2 * k]     = v.x;
            pf[2 * k + 1] = v.y;
        }
#pragma unroll
        for (int j = 2; j < NJ; ++j) {
            const int f = 3 * (j - 2);
            float dx = pf[f + 0] - P[j][0];
            float dy = pf[f + 1] - P[j][1];
            float dz = pf[f + 2] - P[j][2];
            sum += sqrtf(dx * dx + dy * dy + dz * dz);
        }
    }

    // ---- reduction: 4 waves -> wsum -> one atomic per block ----
#pragma unroll
    for (int o = 32; o > 0; o >>= 1) sum += __shfl_down(sum, o, 64);

    const int lane = tid & 63;
    const int wid  = tid >> 6;
    if (lane == 0) wsum[wid] = sum;
    __syncthreads();
    if (tid == 0) {
        atomicAdd(out, (wsum[0] + wsum[1] + wsum[2] + wsum[3]) * scale);
    }
}

extern "C" void kernel_launch(void* const* d_in, const int* in_sizes, int n_in,
                              void* d_out, int out_size, void* d_ws, size_t ws_size,
                              hipStream_t stream) {
    const float4* pred4 = (const float4*)d_in[0];
    const float4* rot4  = (const float4*)d_in[1];
    const float* offsets = (const float*)d_in[2];
    float* out = (float*)d_out;

    int nposes = in_sizes[1] / (NJ * 6);   // B*S = 131072
    float scale = 1000.0f / ((float)nposes * 20.0f);

    hipMemsetAsync(out, 0, sizeof(float), stream);

    int grid = (nposes + TILE - 1) / TILE; // 512 blocks
    mpjpe_fk_kernel<<<grid, 256, 0, stream>>>(pred4, rot4, offsets, out, nposes, scale);
}

// Round 11
// 136.172 us; speedup vs baseline: 1.1251x; 1.0213x over previous
//
#include <hip/hip_runtime.h>

#define NJ 22
#define TILE 112
#define RECB 528                       // gt_rot bytes per pose
#define STAGE_BYTES (TILE * RECB)      // 59136 (static LDS, fits 64KB; 2 blocks/CU)
#define NCHUNK (STAGE_BYTES / 256)     // 231 width-4 chunks (64 lanes x 4B)

__device__ __forceinline__ void rot6d_to_mat(float a1x, float a1y, float a1z,
                                             float a2x, float a2y, float a2z,
                                             float* R) {
    float n1 = sqrtf(a1x * a1x + a1y * a1y + a1z * a1z);
    float inv1 = 1.0f / fmaxf(n1, 1e-12f);
    float b1x = a1x * inv1, b1y = a1y * inv1, b1z = a1z * inv1;
    float d = b1x * a2x + b1y * a2y + b1z * a2z;
    float b2x = a2x - b1x * d, b2y = a2y - b1y * d, b2z = a2z - b1z * d;
    float n2 = sqrtf(b2x * b2x + b2y * b2y + b2z * b2z);
    float inv2 = 1.0f / fmaxf(n2, 1e-12f);
    b2x *= inv2; b2y *= inv2; b2z *= inv2;
    float b3x = b1y * b2z - b1z * b2y;
    float b3y = b1z * b2x - b1x * b2z;
    float b3z = b1x * b2y - b1y * b2x;
    R[0] = b1x; R[1] = b2x; R[2] = b3x;
    R[3] = b1y; R[4] = b2y; R[5] = b3y;
    R[6] = b1z; R[7] = b2z; R[8] = b3z;
}

__device__ __forceinline__ void matmul3(const float* __restrict__ A,
                                        const float* __restrict__ B,
                                        float* __restrict__ C) {
#pragma unroll
    for (int r = 0; r < 3; ++r) {
#pragma unroll
        for (int c = 0; c < 3; ++c) {
            C[r * 3 + c] = A[r * 3 + 0] * B[0 * 3 + c]
                         + A[r * 3 + 1] * B[1 * 3 + c]
                         + A[r * 3 + 2] * B[2 * 3 + c];
        }
    }
}

// async global->LDS, 4B per lane: lane i fills lds_base + 4*i from its own gaddr.
__device__ __forceinline__ void g2lds4(const void* g, void* l) {
    __builtin_amdgcn_global_load_lds(
        (const __attribute__((address_space(1))) unsigned int*)g,
        (__attribute__((address_space(3))) unsigned int*)l,
        4, 0, 0);
}

// FK + distance sum for one pose. rec = 30 float2 (joints 2..21, 6 floats each),
// backed by LDS (staged path) or a register array (fallback) — fully unrolled,
// all indices compile-time.
__device__ __forceinline__ float fk_dist_sum(const float2* __restrict__ rec,
                                             const float* __restrict__ pf,
                                             const float* __restrict__ off) {
    constexpr int PAR[NJ] = {-1, 0, 0, 0, 1, 2, 3, 4, 5, 6, 7, 8, 9, 9, 9, 12, 13, 14, 16, 17, 18, 19};
    float R[NJ][9];
    float P[NJ][3];
    R[0][0] = 1.f; R[0][1] = 0.f; R[0][2] = 0.f;
    R[0][3] = 0.f; R[0][4] = 1.f; R[0][5] = 0.f;
    R[0][6] = 0.f; R[0][7] = 0.f; R[0][8] = 1.f;
    P[0][0] = 0.f; P[0][1] = 0.f; P[0][2] = 0.f;

    float sum = 0.0f;
#pragma unroll
    for (int i = 1; i < NJ; ++i) {
        const int p = PAR[i];
        float ox = off[i * 3 + 0];
        float oy = off[i * 3 + 1];
        float oz = off[i * 3 + 2];
#pragma unroll
        for (int r = 0; r < 3; ++r) {
            P[i][r] = P[p][r] + R[p][r * 3 + 0] * ox
                              + R[p][r * 3 + 1] * oy
                              + R[p][r * 3 + 2] * oz;
        }
        if (i == 1) {
#pragma unroll
            for (int k = 0; k < 9; ++k) R[i][k] = R[p][k];
        } else if (i < NJ - 1) {            // R[21] is never consumed
            const int s = 3 * (i - 2);      // compile-time after unroll
            float2 v0 = rec[s + 0];
            float2 v1 = rec[s + 1];
            float2 v2 = rec[s + 2];
            float M[9];
            rot6d_to_mat(v0.x, v0.y, v1.x, v1.y, v2.x, v2.y, M);
            matmul3(R[p], M, R[i]);
        }
        if (i >= 2) {
            const int f = 3 * (i - 2);
            float dx = pf[f + 0] - P[i][0];
            float dy = pf[f + 1] - P[i][1];
            float dz = pf[f + 2] - P[i][2];
            sum += sqrtf(dx * dx + dy * dy + dz * dz);
        }
    }
    return sum;
}

// Block = 256 threads. Full tiles: all 4 waves issue 231 async width-4
// global_load_lds chunks (contiguous 112-pose gt_rot slab -> linear LDS),
// one barrier drains vmcnt, then waves 0-1 run FK out of LDS (one pose per
// thread). pred is per-thread scattered but issued at kernel top so its
// latency hides under staging. Partial last tile: block-uniform scattered
// fallback (same FK over a register array). Rationale: r9/r10 showed
// reg-roundtrip staging loses; global_load_lds is the async-DMA path the
// compiler never emits on its own (m97: +69% from this alone).
__global__ __launch_bounds__(256) void mpjpe_fk_kernel(
    const float4* __restrict__ pred4,     // [NP*15] (=[NP,20,3] floats)
    const float* __restrict__ gt_rot,     // [NP*132] (=[NP,22,6] floats)
    const float* __restrict__ offsets,    // [22,3]
    float* __restrict__ out,              // [1]
    int nposes, float scale)              // scale = 1000 / (NP*20)
{
    __shared__ char smem[STAGE_BYTES];
    __shared__ float wsum[4];

    const int tid  = threadIdx.x;
    const int lane = tid & 63;
    const int wid  = tid >> 6;
    const int base = blockIdx.x * TILE;
    const int pose = base + tid;
    const bool mine = (tid < TILE) && (pose < nposes);

    // ---- early per-thread pred prefetch (latency hides under staging) ----
    float pf[60];
    if (mine) {
        const float4* pp = pred4 + (size_t)pose * 15;
#pragma unroll
        for (int k = 0; k < 15; ++k) {
            float4 v = pp[k];
            pf[4*k+0] = v.x; pf[4*k+1] = v.y; pf[4*k+2] = v.z; pf[4*k+3] = v.w;
        }
    }
    __builtin_amdgcn_sched_barrier(0);   // pin: pred loads issue before staging

    float sum = 0.0f;

    if (base + TILE <= nposes) {
        // ---------- staged path (full tile) ----------
        const char* gbase = (const char*)gt_rot + (size_t)base * RECB;
        for (int n = wid; n < NCHUNK; n += 4) {            // 58/58/58/57 per wave
            g2lds4(gbase + n * 256 + lane * 4, smem + n * 256);
        }
        __syncthreads();                                    // drains vmcnt: LDS ready

        if (tid < TILE) {
            const float2* rec = (const float2*)(smem + tid * RECB + 48); // joint 2
            sum = fk_dist_sum(rec, pf, offsets);
        }
    } else {
        // ---------- fallback path (partial tile, block-uniform) ----------
        if (mine) {
            const float2* g2 = (const float2*)(gt_rot + (size_t)pose * 132 + 12);
            float2 lr[30];
#pragma unroll
            for (int k = 0; k < 30; ++k) lr[k] = g2[k];
            sum = fk_dist_sum(lr, pf, offsets);
        }
    }

    // ---- reduction: wave shuffle -> wsum -> one atomic per block ----
#pragma unroll
    for (int o = 32; o > 0; o >>= 1) sum += __shfl_down(sum, o, 64);

    if (lane == 0) wsum[wid] = sum;
    __syncthreads();
    if (tid == 0) {
        atomicAdd(out, (wsum[0] + wsum[1] + wsum[2] + wsum[3]) * scale);
    }
}

extern "C" void kernel_launch(void* const* d_in, const int* in_sizes, int n_in,
                              void* d_out, int out_size, void* d_ws, size_t ws_size,
                              hipStream_t stream) {
    const float4* pred4  = (const float4*)d_in[0];
    const float* gt_rot  = (const float*)d_in[1];
    const float* offsets = (const float*)d_in[2];
    float* out = (float*)d_out;

    int nposes = in_sizes[1] / (NJ * 6);   // B*S = 131072
    float scale = 1000.0f / ((float)nposes * 20.0f);

    hipMemsetAsync(out, 0, sizeof(float), stream);

    int grid = (nposes + TILE - 1) / TILE; // 1171 blocks
    mpjpe_fk_kernel<<<grid, 256, 0, stream>>>(pred4, gt_rot, offsets, out, nposes, scale);
}